// Round 5
// baseline (166.038 us; speedup 1.0000x reference)
//
#include <hip/hip_runtime.h>

// NoisyTopExpertsPerItemRouter: G=32,S=1024,H=2048,E=64,K=2 (top-2)
// Outputs (concat, f32): idx (N*2) | w (N*2) | aux (1) | probs (N*64)
//
// Split-precision bf16 MFMA (R3/R4-proven numerics):
//   a = ah + 2^-8*am, w = wh + 2^-8*wm; logits = accM + 2^-8*accS
// A staged row-major f32 via global_load_lds (1KB-contiguous HBM reads),
// decomposed in-register per wave; W pre-decomposed fragment-linear (L2).

constexpr int GS   = 32768;
constexpr int EXPN = 64;
constexpr int HID  = 2048;
constexpr int BM   = 64;              // rows per block (4 waves x 16)
constexpr int BK   = 128;             // K chunk (512B contiguous per row)
constexpr int NCH  = HID / BK;        // 16 chunks
constexpr int GSTRIDE_F = 260;        // floats per 2-row LDS group (1040B: 16B-aligned, bank-spread)
constexpr int BUFBYTES  = 32 * GSTRIDE_F * 4;   // 33280 B per staging buffer

typedef __attribute__((ext_vector_type(8))) short s16x8;
typedef __attribute__((ext_vector_type(4))) float f32x4;

#define AS_GLOBAL(p) ((const __attribute__((address_space(1))) void*)(p))
#define AS_LDS(p)    ((__attribute__((address_space(3))) void*)(p))

__device__ __forceinline__ void decomp8(float4 x0, float4 x1, s16x8& h, s16x8& m)
{
    float v[8] = {x0.x,x0.y,x0.z,x0.w,x1.x,x1.y,x1.z,x1.w};
    #pragma unroll
    for (int i = 0; i < 8; ++i) {
        union { float f; unsigned u; } a; a.f = v[i];
        unsigned hb = (a.u + 0x7fffu + ((a.u >> 16) & 1u)) >> 16;  // RNE bf16
        union { unsigned u; float f; } hf; hf.u = hb << 16;
        float r = (v[i] - hf.f) * 256.f;         // exact residual, scaled 2^8
        union { float f; unsigned u; } rb; rb.f = r;
        h[i] = (short)hb;
        m[i] = (short)(rb.u >> 16);
    }
}

// W fragments: frag f = cs*256 + nt*64 + lane encodes
//   expert e = nt*16 + (lane&15), k = cs*32 + (lane>>4)*8 + j (j=0..7)
__global__ __launch_bounds__(256)
void prep_kernel(const float* __restrict__ W, short* __restrict__ WhF,
                 short* __restrict__ WmF)
{
    const int t  = blockIdx.x * 256 + threadIdx.x;   // 0..16383
    const int cs = t >> 8;
    const int nt = (t >> 6) & 3;
    const int l  = t & 63;
    const int e  = nt * 16 + (l & 15);
    const int kb = cs * 32 + ((l >> 4) << 3);
    const float* p = W + (size_t)e * HID + kb;
    float4 x0 = *(const float4*)p;
    float4 x1 = *(const float4*)(p + 4);
    s16x8 h, m;
    decomp8(x0, x1, h, m);
    *(s16x8*)&WhF[(size_t)t * 8] = h;
    *(s16x8*)&WmF[(size_t)t * 8] = m;
}

__global__ __launch_bounds__(256, 2)
void router_kernel(const float* __restrict__ tokens,
                   const float* __restrict__ noise,
                   const float* __restrict__ bias,
                   const s16x8* __restrict__ WhF,
                   const s16x8* __restrict__ WmF,
                   float* __restrict__ out,
                   float* __restrict__ ws)
{
    // staging: 2 buffers x 32 groups x (2 rows x 128 floats + 4 pad floats)
    // group g holds rows 2g,2g+1 of the block tile; addr(r,k) =
    //   (r>>1)*1040B + (r&1)*512B + k*4B.  After the K-loop, buffer 0 is
    //   reused for lg[64][65] + red[8][64] (aliased; safe post-barrier).
    __shared__ __align__(16) char smem[2 * BUFBYTES];

    const int tid  = threadIdx.x;
    const int lane = tid & 63;
    const int wv   = tid >> 6;          // wave id = row-tile (M-split)
    const int row0 = blockIdx.x * BM;

    const float* tok_base = tokens + (size_t)row0 * HID;

    f32x4 accM[4], accS[4];
    #pragma unroll
    for (int nt = 0; nt < 4; ++nt) { accM[nt] = (f32x4)0.f; accS[nt] = (f32x4)0.f; }

    // stage chunk (kb) into buffer b: 8 instrs/wave, each 1KB contiguous HBM
    auto stage = [&](int b, int kb) {
        char* base = smem + b * BUFBYTES;
        #pragma unroll
        for (int i = 0; i < 8; ++i) {
            const int g = wv * 8 + i;                 // rows 2g, 2g+1
            const int r = 2 * g + (lane >> 5);
            const float* src = tok_base + (size_t)r * HID + kb + (lane & 31) * 4;
            __builtin_amdgcn_global_load_lds(AS_GLOBAL(src),
                                             AS_LDS(base + g * 1040), 16, 0, 0);
        }
    };

    stage(0, 0);
    __syncthreads();

    // my fragment rows: r = wv*16 + (lane&15); k-slice (lane>>4)*8
    const int fr   = wv * 16 + (lane & 15);
    const int foff = (fr >> 1) * GSTRIDE_F + (fr & 1) * 128 + ((lane >> 4) << 3);

    int buf = 0;
    for (int c = 0; c < NCH; ++c) {
        if (c + 1 < NCH) stage(buf ^ 1, (c + 1) * BK);

        const float* Ab = (const float*)(smem + buf * BUFBYTES);
        #pragma unroll
        for (int s = 0; s < 4; ++s) {
            const float* fp = Ab + foff + s * 32;
            float4 x0 = *(const float4*)fp;
            float4 x1 = *(const float4*)(fp + 4);
            s16x8 ah, am;
            decomp8(x0, x1, ah, am);
            const int cs = c * 4 + s;
            #pragma unroll
            for (int nt = 0; nt < 4; ++nt) {
                s16x8 bh = WhF[cs * 256 + nt * 64 + lane];
                s16x8 bm = WmF[cs * 256 + nt * 64 + lane];
                accM[nt] = __builtin_amdgcn_mfma_f32_16x16x32_bf16(ah, bh, accM[nt], 0, 0, 0);
                accS[nt] = __builtin_amdgcn_mfma_f32_16x16x32_bf16(ah, bm, accS[nt], 0, 0, 0);
                accS[nt] = __builtin_amdgcn_mfma_f32_16x16x32_bf16(am, bh, accS[nt], 0, 0, 0);
            }
        }
        __syncthreads();   // drains staging vmcnt; next buffer ready
        buf ^= 1;
    }

    // ---- epilogue workspace aliases staging buffer 0 ----
    float (*lg)[EXPN + 1] = (float (*)[EXPN + 1])smem;
    float (*red)[EXPN]    = (float (*)[EXPN])(smem + BM * (EXPN + 1) * 4);

    // C/D layout: col = lane&15, row = (lane>>4)*4 + reg  [m89-verified]
    #pragma unroll
    for (int nt = 0; nt < 4; ++nt)
        #pragma unroll
        for (int r = 0; r < 4; ++r)
            lg[wv * 16 + (lane >> 4) * 4 + r][nt * 16 + (lane & 15)]
                = accM[nt][r] + 0.00390625f * accS[nt][r];
    __syncthreads();

    float* out_idx   = out;
    float* out_w     = out + 2 * GS;
    float* out_probs = out + 4 * GS + 1;

    const float blane = bias[lane];
    float impL = 0.f, cntL = 0.f;

    for (int rr = 0; rr < 16; ++rr) {
        const int r = (wv << 4) + rr;
        const size_t row = (size_t)row0 + r;
        float v = lg[r][lane] + blane + noise[row * EXPN + lane];

        float m = v;
        #pragma unroll
        for (int off = 32; off >= 1; off >>= 1)
            m = fmaxf(m, __shfl_xor(m, off));
        float e = expf(v - m);
        float s = e;
        #pragma unroll
        for (int off = 32; off >= 1; off >>= 1)
            s += __shfl_xor(s, off);
        float p = e / s;

        out_probs[row * EXPN + lane] = p;
        impL += p;
        cntL += (p > 0.f) ? 1.f : 0.f;

        float v1 = p; int i1 = lane;
        #pragma unroll
        for (int off = 32; off >= 1; off >>= 1) {
            float ov = __shfl_xor(v1, off);
            int   oi = __shfl_xor(i1, off);
            if (ov > v1 || (ov == v1 && oi < i1)) { v1 = ov; i1 = oi; }
        }
        float v2 = (lane == i1) ? -1.f : p; int i2 = lane;
        #pragma unroll
        for (int off = 32; off >= 1; off >>= 1) {
            float ov = __shfl_xor(v2, off);
            int   oi = __shfl_xor(i2, off);
            if (ov > v2 || (ov == v2 && oi < i2)) { v2 = ov; i2 = oi; }
        }
        if (lane == 0) {
            float denom = v1 + v2 + 1e-9f;
            out_idx[row * 2 + 0] = (float)i1;
            out_idx[row * 2 + 1] = (float)i2;
            out_w[row * 2 + 0] = v1 / denom;
            out_w[row * 2 + 1] = v2 / denom;
        }
    }

    red[wv][lane]     = impL;
    red[4 + wv][lane] = cntL;
    __syncthreads();
    if (tid < EXPN) {
        float t1 = red[0][tid] + red[1][tid] + red[2][tid] + red[3][tid];
        float t2 = red[4][tid] + red[5][tid] + red[6][tid] + red[7][tid];
        atomicAdd(&ws[tid], t1);
        atomicAdd(&ws[EXPN + tid], t2);
    }
}

__global__ void aux_kernel(const float* __restrict__ ws, float* __restrict__ out)
{
    const int lane = threadIdx.x;  // 64 threads
    float x = ws[lane] * ws[EXPN + lane];   // importance * load
    float s = x;
    #pragma unroll
    for (int off = 32; off >= 1; off >>= 1)
        s += __shfl_xor(s, off);
    float mean = s * (1.f / 64.f);
    float d = x - mean;
    float ss = d * d;
    #pragma unroll
    for (int off = 32; off >= 1; off >>= 1)
        ss += __shfl_xor(ss, off);
    if (lane == 0)
        out[4 * GS] = 0.01f * (ss / 63.f);   // unbiased var * 0.01
}

extern "C" void kernel_launch(void* const* d_in, const int* in_sizes, int n_in,
                              void* d_out, int out_size, void* d_ws, size_t ws_size,
                              hipStream_t stream)
{
    const float* tokens = (const float*)d_in[0];
    const float* noise  = (const float*)d_in[1];
    const float* W      = (const float*)d_in[2];
    const float* bias   = (const float*)d_in[3];
    float* out = (float*)d_out;
    float* ws  = (float*)d_ws;

    // ws layout: [0..127] f32 imp/cnt accumulators | WhF (256KB) | WmF (256KB)
    short* WhF = (short*)(ws + 128);
    short* WmF = WhF + (size_t)EXPN * HID;

    hipMemsetAsync(ws, 0, 2 * EXPN * sizeof(float), stream);
    prep_kernel<<<EXPN * HID / 8 / 256, 256, 0, stream>>>(W, WhF, WmF);
    router_kernel<<<GS / BM, 256, 0, stream>>>(tokens, noise, bias,
                                               (const s16x8*)WhF, (const s16x8*)WmF,
                                               out, ws);
    aux_kernel<<<1, 64, 0, stream>>>(ws, out);
}